// Round 1
// baseline (130.964 us; speedup 1.0000x reference)
//
#include <hip/hip_runtime.h>

static constexpr int   NCLS       = 2;
static constexpr float F_IOU_TR   = 0.3f;
static constexpr float F_SCORE_TR = 0.0f;
static constexpr float F_EPS      = 1e-7f;

// Pack (score, idx) into a u64 whose unsigned order == (score asc, idx desc).
// Scores are >= 0 here (selected scores pass SCORE_TR=0), so the raw float
// bit pattern is monotone. ~idx makes the SMALLER index win on score ties
// (jnp.argmax = first occurrence).
__device__ __forceinline__ unsigned long long pack_cand(float score, unsigned int idx) {
    return ((unsigned long long)__float_as_uint(score) << 32) |
           (unsigned long long)(~idx);
}

__device__ __forceinline__ unsigned int unpack_idx(unsigned long long p) {
    return ~(unsigned int)(p & 0xFFFFFFFFull);
}

// Wave(64) shuffle reduce + 4-wave LDS reduce, then one atomicMax per class.
__device__ __forceinline__ void block_reduce_max2(unsigned long long b0,
                                                  unsigned long long b1,
                                                  unsigned long long* dst0,
                                                  unsigned long long* dst1) {
    __shared__ unsigned long long smem[4][2];
#pragma unroll
    for (int off = 32; off > 0; off >>= 1) {
        unsigned long long o0 = __shfl_down(b0, (unsigned)off, 64);
        unsigned long long o1 = __shfl_down(b1, (unsigned)off, 64);
        if (o0 > b0) b0 = o0;
        if (o1 > b1) b1 = o1;
    }
    const int wave = threadIdx.x >> 6;
    const int lane = threadIdx.x & 63;
    if (lane == 0) { smem[wave][0] = b0; smem[wave][1] = b1; }
    __syncthreads();
    if (threadIdx.x == 0) {
        unsigned long long m0 = smem[0][0], m1 = smem[0][1];
#pragma unroll
        for (int w = 1; w < 4; ++w) {
            if (smem[w][0] > m0) m0 = smem[w][0];
            if (smem[w][1] > m1) m1 = smem[w][1];
        }
        atomicMax(dst0, m0);
        atomicMax(dst1, m1);
    }
}

// Pass 1: per-class argmax of score (sel = cls==c && score>=SCORE_TR).
__global__ __launch_bounds__(256) void nms_pass1(const float* __restrict__ res, int N,
                                                 unsigned long long* __restrict__ ws) {
    unsigned long long b0 = 0ull, b1 = 0ull;
    const int stride = gridDim.x * blockDim.x;
    for (int i = blockIdx.x * blockDim.x + threadIdx.x; i < N; i += stride) {
        float2 sc = *reinterpret_cast<const float2*>(res + (size_t)i * 8);
        if (sc.x >= F_SCORE_TR) {
            unsigned long long p = pack_cand(sc.x, (unsigned int)i);
            if (sc.y < 0.5f) { if (p > b0) b0 = p; }
            else             { if (p > b1) b1 = p; }
        }
    }
    block_reduce_max2(b0, b1, &ws[0], &ws[1]);
}

// Pass 2: per-class argmax of score among boxes with IoU(b0, box) <= IOU_TR.
__global__ __launch_bounds__(256) void nms_pass2(const float* __restrict__ res, int N,
                                                 unsigned long long* __restrict__ ws) {
    // Decode each class's top box (written by pass 1; kernel boundary => visible).
    const unsigned int ia = unpack_idx(ws[0]);
    const unsigned int ic = unpack_idx(ws[1]);
    const float* pa = res + (size_t)ia * 8 + 2;
    const float* pc = res + (size_t)ic * 8 + 2;
    const float a0x = pa[0], a0y = pa[1], a0z = pa[2], a1x = pa[3], a1y = pa[4], a1z = pa[5];
    const float c0x = pc[0], c0y = pc[1], c0z = pc[2], c1x = pc[3], c1y = pc[4], c1z = pc[5];
    const float va = ((a1x - a0x) * (a1y - a0y)) * (a1z - a0z);
    const float vc = ((c1x - c0x) * (c1y - c0y)) * (c1z - c0z);

    unsigned long long b0 = 0ull, b1 = 0ull;
    const int stride = gridDim.x * blockDim.x;
    for (int i = blockIdx.x * blockDim.x + threadIdx.x; i < N; i += stride) {
        const float4* rp = reinterpret_cast<const float4*>(res + (size_t)i * 8);
        const float4 r0 = rp[0];   // score, cls, x1, y1
        const float4 r1 = rp[1];   // z1, x2, y2, z2
        const float score = r0.x;
        const bool  is1   = (r0.y >= 0.5f);

        // Select this class's reference box (scalar selects, no runtime-indexed arrays).
        const float blx = is1 ? c0x : a0x;
        const float bly = is1 ? c0y : a0y;
        const float blz = is1 ? c0z : a0z;
        const float bhx = is1 ? c1x : a1x;
        const float bhy = is1 ? c1y : a1y;
        const float bhz = is1 ? c1z : a1z;
        const float v1  = is1 ? vc  : va;

        const float lox = fmaxf(blx, r0.z);
        const float loy = fmaxf(bly, r0.w);
        const float loz = fmaxf(blz, r1.x);
        const float hix = fminf(bhx, r1.y);
        const float hiy = fminf(bhy, r1.z);
        const float hiz = fminf(bhz, r1.w);
        const float inter = (fmaxf(hix - lox, 0.0f) * fmaxf(hiy - loy, 0.0f)) * fmaxf(hiz - loz, 0.0f);
        const float v2    = ((r1.y - r0.z) * (r1.z - r0.w)) * (r1.w - r1.x);
        const float iou   = inter / (v1 + v2 - inter + F_EPS);

        if (score >= F_SCORE_TR && iou <= F_IOU_TR) {
            unsigned long long p = pack_cand(score, (unsigned int)i);
            if (is1) { if (p > b1) b1 = p; }
            else     { if (p > b0) b0 = p; }
        }
    }
    block_reduce_max2(b0, b1, &ws[2], &ws[3]);
}

// Output rows: [c0:i0, c0:i1, c1:i0, c1:i1] x 8 cols = 32 floats.
__global__ void nms_write(const float* __restrict__ res,
                          const unsigned long long* __restrict__ ws,
                          float* __restrict__ out) {
    const int t = threadIdx.x;
    if (t >= 32) return;
    const int row  = t >> 3;
    const int col  = t & 7;
    const int slot = (row == 0) ? 0 : (row == 1) ? 2 : (row == 2) ? 1 : 3;
    const unsigned int idx = unpack_idx(ws[slot]);
    out[t] = res[(size_t)idx * 8 + col];
}

extern "C" void kernel_launch(void* const* d_in, const int* in_sizes, int n_in,
                              void* d_out, int out_size, void* d_ws, size_t ws_size,
                              hipStream_t stream) {
    const float* res = (const float*)d_in[0];
    const int N = in_sizes[0] / 8;
    unsigned long long* ws = (unsigned long long*)d_ws;

    // ws[0..1]: per-class packed argmax (pass 1); ws[2..3]: post-NMS argmax (pass 2).
    hipMemsetAsync(d_ws, 0, 4 * sizeof(unsigned long long), stream);

    const int threads = 256;
    int blocks = (N + threads - 1) / threads;
    if (blocks > 2048) blocks = 2048;

    nms_pass1<<<blocks, threads, 0, stream>>>(res, N, ws);
    nms_pass2<<<blocks, threads, 0, stream>>>(res, N, ws);
    nms_write<<<1, 64, 0, stream>>>(res, ws, (float*)d_out);
}